// Round 5
// baseline (489.173 us; speedup 1.0000x reference)
//
#include <hip/hip_runtime.h>
#include <hip/hip_bf16.h>
#include <cstdint>
#include <type_traits>

typedef __attribute__((ext_vector_type(8))) short short8;
typedef __attribute__((ext_vector_type(4))) float floatx4;

constexpr int S_LEN = 2048;
constexpr float ATTN_SCALE = 0.08838834764831845f;  // 128^-0.5
constexpr float LOG2E = 1.4426950408889634f;
constexpr float CP = ATTN_SCALE * LOG2E;            // fold scale into exp2 arg

// ---------------------------------------------------------------- async G->LDS
__device__ __forceinline__ void gl_lds16(const void* gp, void* lp) {
  __builtin_amdgcn_global_load_lds(
      (__attribute__((address_space(1))) void*)(uintptr_t)gp,
      (__attribute__((address_space(3))) void*)lp,
      16, 0, 0);
}

// ------------------------------------------------ 16-lane max via DPP row_ror
__device__ __forceinline__ float rowmax16(float x) {
  union { float f; int i; } a, b;
  a.f = x;
  b.i = __builtin_amdgcn_update_dpp(0, a.i, 0x121, 0xF, 0xF, true);  // ror:1
  x = fmaxf(x, b.f); a.f = x;
  b.i = __builtin_amdgcn_update_dpp(0, a.i, 0x122, 0xF, 0xF, true);  // ror:2
  x = fmaxf(x, b.f); a.f = x;
  b.i = __builtin_amdgcn_update_dpp(0, a.i, 0x124, 0xF, 0xF, true);  // ror:4
  x = fmaxf(x, b.f); a.f = x;
  b.i = __builtin_amdgcn_update_dpp(0, a.i, 0x128, 0xF, 0xF, true);  // ror:8
  return fmaxf(x, b.f);
}

// ------------------------------------------------------------- fused prologue
// blocks [0,8192): x fp32 -> bf16 (float4/thread)
// blocks [8192,12288): Wq transpose  [2048][2048] -> wqkvt[0..]
// blocks [12288,13312): Wk transpose [2048][512]  -> wqkvt + 2048*2048
// blocks [13312,14336): Wv transpose [2048][512]  -> wqkvt + 2560*2048
// blocks [14336,18432): Wo transpose [2048][2048] -> wot
__device__ __forceinline__ void tr32(const float* __restrict__ src,
                                     __hip_bfloat16* __restrict__ dst,
                                     int blk, int nblk_x, int N, int tid,
                                     float (*tile)[33]) {
  int n0 = (blk % nblk_x) * 32, k0 = (blk / nblk_x) * 32;
  int tx = tid & 31, ty = tid >> 5;   // (32, 8)
#pragma unroll
  for (int i = ty; i < 32; i += 8)
    tile[i][tx] = src[(size_t)(k0 + i) * N + n0 + tx];
  __syncthreads();
#pragma unroll
  for (int i = ty; i < 32; i += 8)
    dst[(size_t)(n0 + i) * 2048 + k0 + tx] = __float2bfloat16(tile[tx][i]);
}

__global__ void prep_kernel(const float* __restrict__ x,
                            const float* __restrict__ Wq,
                            const float* __restrict__ Wk,
                            const float* __restrict__ Wv,
                            const float* __restrict__ Wo,
                            __hip_bfloat16* __restrict__ xb,
                            __hip_bfloat16* __restrict__ wqkvt,
                            __hip_bfloat16* __restrict__ wot) {
  __shared__ float tile[32][33];
  int bx = blockIdx.x, tid = threadIdx.x;
  if (bx < 8192) {
    int i = bx * 256 + tid;           // 2097152 float4s exactly
    float4 f = reinterpret_cast<const float4*>(x)[i];
    union { unsigned long long u64; __hip_bfloat16 h[4]; } u;
    u.h[0] = __float2bfloat16(f.x);
    u.h[1] = __float2bfloat16(f.y);
    u.h[2] = __float2bfloat16(f.z);
    u.h[3] = __float2bfloat16(f.w);
    reinterpret_cast<unsigned long long*>(xb)[i] = u.u64;
  } else if (bx < 12288) {
    tr32(Wq, wqkvt, bx - 8192, 64, 2048, tid, tile);
  } else if (bx < 13312) {
    tr32(Wk, wqkvt + 2048 * 2048, bx - 12288, 16, 512, tid, tile);
  } else if (bx < 14336) {
    tr32(Wv, wqkvt + 2560 * 2048, bx - 13312, 16, 512, tid, tile);
  } else {
    tr32(Wo, wot, bx - 14336, 64, 2048, tid, tile);
  }
}

// ------------------------------------------------------- shared GEMM staging
// 64x128 tile, BK=64. A: 8 wave-instr (chunk = kchunk*64 + row);
// B: 16 wave-instr (chunk = kchunk*128 + row). 24 KB LDS.
// Frags: a[2], b[4]; acc[2][4]. 6 blocks/CU (LDS-limited).
#define GEMM_STAGE(Ab, Bb, Alds, Blds, K, k0)                                   \
  {                                                                             \
    _Pragma("unroll") for (int j = 0; j < 6; ++j) {                             \
      const int i = wave * 6 + j;                                               \
      if (i < 8) {                                                              \
        gl_lds16(Ab + (size_t)lane * (K) + (k0) + i * 8, &Alds[(i * 64 + lane) * 8]); \
      } else {                                                                  \
        const int ii = i - 8, kchunk = ii >> 1, row = ((ii & 1) << 6) | lane;   \
        gl_lds16(Bb + (size_t)row * (K) + (k0) + kchunk * 8,                    \
                 &Blds[(kchunk * 128 + row) * 8]);                              \
      }                                                                         \
    }                                                                           \
  }

#define GEMM_COMPUTE(Alds, Blds)                                                \
  _Pragma("unroll") for (int kk = 0; kk < 2; ++kk) {                            \
    short8 a[2], b[4];                                                          \
    _Pragma("unroll") for (int mi = 0; mi < 2; ++mi)                            \
      a[mi] = *(const short8*)&Alds[(((kk * 4 + quad) * 64) + wm * 32 + mi * 16 + l15) * 8]; \
    _Pragma("unroll") for (int ni = 0; ni < 4; ++ni)                            \
      b[ni] = *(const short8*)&Blds[(((kk * 4 + quad) * 128) + wn * 64 + ni * 16 + l15) * 8]; \
    _Pragma("unroll") for (int mi = 0; mi < 2; ++mi)                            \
      _Pragma("unroll") for (int ni = 0; ni < 4; ++ni)                          \
        acc[mi][ni] = __builtin_amdgcn_mfma_f32_16x16x32_bf16(a[mi], b[ni], acc[mi][ni], 0, 0, 0); \
  }

// ------------------------------------------------------------ QKV GEMM (fused)
// C = xb[4096][2048] @ wqkvt[3072][2048]^T, attention-native outputs:
//   cols 0..2047    -> qbuf[row][col]
//   cols 2048..2559 -> kbuf chunk-transposed tiles (tile=(b*4+kvh)*32+kt):
//                      (kv,d) at tile*8192 + (d>>3)*512 + kv*8 + (d&7)
//   cols 2560..3071 -> vbuf V^T XOR-swizzled tiles:
//                      (kv,d) at tile*8192 + d*64 + (kv ^ ((d&7)<<3))
__global__ __launch_bounds__(256, 4) void qkv_gemm_kernel(
    const __hip_bfloat16* __restrict__ A,
    const __hip_bfloat16* __restrict__ Bt,
    __hip_bfloat16* __restrict__ qbuf,
    __hip_bfloat16* __restrict__ kbuf,
    __hip_bfloat16* __restrict__ vbuf) {
  constexpr int K = 2048;
  __shared__ __align__(16) __hip_bfloat16 lds[4096 + 8192];
  __hip_bfloat16* Alds = lds;
  __hip_bfloat16* Blds = lds + 4096;
  const int tid = threadIdx.x;
  const int wave = tid >> 6, lane = tid & 63;
  const int quad = lane >> 4, l15 = lane & 15;
  const int wm = wave >> 1, wn = wave & 1;
  const int m0 = blockIdx.y * 64, n0 = blockIdx.x * 128;

  floatx4 acc[2][4] = {};
  const __hip_bfloat16* Ab = A + (size_t)m0 * K;
  const __hip_bfloat16* Bb = Bt + (size_t)n0 * K;

  for (int k0 = 0; k0 < K; k0 += 64) {
    GEMM_STAGE(Ab, Bb, Alds, Blds, K, k0)
    __syncthreads();
    GEMM_COMPUTE(Alds, Blds)
    __syncthreads();
  }

  const int region = (n0 - 2048) >> 7;          // valid when n0 >= 2048
  const int kvh = region & 3;
#pragma unroll
  for (int mi = 0; mi < 2; ++mi)
#pragma unroll
    for (int ni = 0; ni < 4; ++ni)
#pragma unroll
      for (int r = 0; r < 4; ++r) {
        int row = m0 + wm * 32 + mi * 16 + quad * 4 + r;
        int col = n0 + wn * 64 + ni * 16 + l15;
        __hip_bfloat16 val = __float2bfloat16(acc[mi][ni][r]);
        if (n0 < 2048) {
          qbuf[(size_t)row * 2048 + col] = val;
        } else {
          int d = wn * 64 + ni * 16 + l15;      // 0..127 within the head
          int s = row & (S_LEN - 1), bb = row >> 11;
          size_t tb = ((size_t)(bb * 4 + kvh) * 32 + (s >> 6)) * 8192;
          int kv = s & 63;
          if (region < 4)
            kbuf[tb + ((d >> 3) << 9) + (kv << 3) + (d & 7)] = val;
          else
            vbuf[tb + d * 64 + (kv ^ ((d & 7) << 3))] = val;
        }
      }
}

// --------------------------------------------------------------- AO GEMM
__global__ __launch_bounds__(256, 4) void gemm_bt_f32_kernel(
    const __hip_bfloat16* __restrict__ A,
    const __hip_bfloat16* __restrict__ Bt,
    float* __restrict__ C, int N, int K) {
  __shared__ __align__(16) __hip_bfloat16 lds[4096 + 8192];
  __hip_bfloat16* Alds = lds;
  __hip_bfloat16* Blds = lds + 4096;
  const int tid = threadIdx.x;
  const int wave = tid >> 6, lane = tid & 63;
  const int quad = lane >> 4, l15 = lane & 15;
  const int wm = wave >> 1, wn = wave & 1;
  const int m0 = blockIdx.y * 64, n0 = blockIdx.x * 128;

  floatx4 acc[2][4] = {};
  const __hip_bfloat16* Ab = A + (size_t)m0 * K;
  const __hip_bfloat16* Bb = Bt + (size_t)n0 * K;

  for (int k0 = 0; k0 < K; k0 += 64) {
    GEMM_STAGE(Ab, Bb, Alds, Blds, K, k0)
    __syncthreads();
    GEMM_COMPUTE(Alds, Blds)
    __syncthreads();
  }

#pragma unroll
  for (int mi = 0; mi < 2; ++mi)
#pragma unroll
    for (int ni = 0; ni < 4; ++ni)
#pragma unroll
      for (int r = 0; r < 4; ++r) {
        int row = m0 + wm * 32 + mi * 16 + quad * 4 + r;
        int col = n0 + wn * 64 + ni * 16 + l15;
        C[(size_t)row * N + col] = acc[mi][ni][r];
      }
}

// --------------------------------------------------------------------- RoPE
// out[d] = x[d]*cos[d>>1] - x[d+64]*sin[d>>1]
// out[d+64] = x[d+64]*cos[32+(d>>1)] + x[d]*sin[32+(d>>1)]
__device__ __forceinline__ void rope8(short8 x0, short8 x1, const float* ca,
                                      const float* sa, const float* cb,
                                      const float* sb, short8& y0, short8& y1) {
#pragma unroll
  for (int e = 0; e < 8; ++e) {
    union { short s; __hip_bfloat16 h; } u0, u1, w0, w1;
    u0.s = x0[e]; u1.s = x1[e];
    float f0 = __bfloat162float(u0.h), f1 = __bfloat162float(u1.h);
    int j = e >> 1;
    w0.h = __float2bfloat16(f0 * ca[j] - f1 * sa[j]);
    w1.h = __float2bfloat16(f1 * cb[j] + f0 * sb[j]);
    y0[e] = w0.s; y1[e] = w1.s;
  }
}

// blocks [0,2048): Q rope; blocks [2048,2560): K rope (tile layout)
__global__ void rope_kernel(__hip_bfloat16* __restrict__ qbuf,
                            __hip_bfloat16* __restrict__ kbuf,
                            const float* __restrict__ cosb,
                            const float* __restrict__ sinb) {
  int bx = blockIdx.x, tid = threadIdx.x;
  float ca[4], sa[4], cb[4], sb[4];
  if (bx < 2048) {
    int t = bx * 256 + tid;            // 4096*16*8 threads
    int c8 = t & 7;
    int head = (t >> 3) & 15;
    int row = t >> 7;
    int s = row & (S_LEN - 1);
    size_t base = (size_t)row * 2048 + head * 128 + c8 * 8;
    short8 x0 = *(const short8*)(qbuf + base);
    short8 x1 = *(const short8*)(qbuf + base + 64);
    *(float4*)ca = *(const float4*)&cosb[s * 64 + c8 * 4];
    *(float4*)sa = *(const float4*)&sinb[s * 64 + c8 * 4];
    *(float4*)cb = *(const float4*)&cosb[s * 64 + 32 + c8 * 4];
    *(float4*)sb = *(const float4*)&sinb[s * 64 + 32 + c8 * 4];
    short8 y0, y1;
    rope8(x0, x1, ca, sa, cb, sb, y0, y1);
    *(short8*)(qbuf + base) = y0;
    *(short8*)(qbuf + base + 64) = y1;
  } else {
    int t = (bx - 2048) * 256 + tid;   // 8*32*64*8 threads
    int c8 = t & 7;
    int kv = (t >> 3) & 63;
    int tile = t >> 9;                 // (b*4+kvh)*32 + kt
    int s = (tile & 31) * 64 + kv;
    size_t a0 = (size_t)tile * 8192 + c8 * 512 + kv * 8;
    short8 x0 = *(const short8*)(kbuf + a0);
    short8 x1 = *(const short8*)(kbuf + a0 + 4096);
    *(float4*)ca = *(const float4*)&cosb[s * 64 + c8 * 4];
    *(float4*)sa = *(const float4*)&sinb[s * 64 + c8 * 4];
    *(float4*)cb = *(const float4*)&cosb[s * 64 + 32 + c8 * 4];
    *(float4*)sb = *(const float4*)&sinb[s * 64 + 32 + c8 * 4];
    short8 y0, y1;
    rope8(x0, x1, ca, sa, cb, sb, y0, y1);
    *(short8*)(kbuf + a0) = y0;
    *(short8*)(kbuf + a0 + 4096) = y1;
  }
}

// ---------------------------------------------------------------- attention
// grid (16, 32), 256 thr. Block = 128 q-rows (2 rowsets of 64) x one head.
// K,V: double-buffered coalesced global_load_lds DMA (K chunk-transposed,
// V transposed+XOR-swizzled). One barrier per KV tile.
// Both rowsets' P computed first (same P region, same-wave DS ordering),
// then one fused PV pass sharing each V fragment across rowsets.
__global__ __launch_bounds__(256, 2) void attn_kernel(
    const __hip_bfloat16* __restrict__ qbuf,   // [4096][2048]
    const __hip_bfloat16* __restrict__ kbuf,   // tiles
    const __hip_bfloat16* __restrict__ vbuf,   // tiles
    __hip_bfloat16* __restrict__ aout) {       // [4096][2048]
  const int qt = (blockIdx.y & 16) ? blockIdx.x : (15 - blockIdx.x);
  const int bh = blockIdx.y;
  const int b = bh >> 4, h = bh & 15;
  const int kvh = h >> 2;

  __shared__ __align__(16) __hip_bfloat16 Kbuf[2][8192];      // 2 x 16 KB
  __shared__ __align__(16) __hip_bfloat16 Vbuf[2][8192];      // 2 x 16 KB
  __shared__ __align__(16) __hip_bfloat16 Plds[4 * 16 * 72];  // 9 KB

  const int tid = threadIdx.x;
  const int wave = tid >> 6, lane = tid & 63;
  const int quad = lane >> 4, l15 = lane & 15;

  short8 qfrag[2][4];
#pragma unroll
  for (int rs = 0; rs < 2; ++rs)
#pragma unroll
    for (int kc = 0; kc < 4; ++kc)
      qfrag[rs][kc] = *(const short8*)(qbuf +
          (size_t)(b * S_LEN + qt * 128 + rs * 64 + wave * 16 + l15) * 2048 +
          h * 128 + kc * 32 + quad * 8);

  const __hip_bfloat16* ktiles = kbuf + (size_t)(b * 4 + kvh) * 32 * 8192;
  const __hip_bfloat16* vtiles = vbuf + (size_t)(b * 4 + kvh) * 32 * 8192;
  const int nt = 2 * qt + 2;

#pragma unroll
  for (int j = 0; j < 4; ++j) {
    int c = tid + 256 * j;
    gl_lds16(ktiles + c * 8, &Kbuf[0][c * 8]);
    gl_lds16(vtiles + c * 8, &Vbuf[0][c * 8]);
  }

  float m_r[2][4];
  floatx4 o[2][8] = {};
  floatx4 o_l[2] = {};
#pragma unroll
  for (int rs = 0; rs < 2; ++rs)
#pragma unroll
    for (int r = 0; r < 4; ++r) m_r[rs][r] = -1e30f;

  short8 onesb;
#pragma unroll
  for (int e = 0; e < 8; ++e) onesb[e] = (short)0x3F80;  // bf16 1.0

  __hip_bfloat16* pw = &Plds[wave * 16 * 72];

  for (int kt = 0; kt < nt; ++kt) {
    const int cur = kt & 1;
    __syncthreads();   // K(kt)/V(kt) DMA drained & visible

    if (kt + 1 < nt) {
      const __hip_bfloat16* kb = ktiles + (size_t)(kt + 1) * 8192;
      const __hip_bfloat16* vb = vtiles + (size_t)(kt + 1) * 8192;
#pragma unroll
      for (int j = 0; j < 4; ++j) {
        int c = tid + 256 * j;
        gl_lds16(kb + c * 8, &Kbuf[1 - cur][c * 8]);
        gl_lds16(vb + c * 8, &Vbuf[1 - cur][c * 8]);
      }
    }

    // S = Q K^T for both rowsets (K frags loaded once, used twice)
    floatx4 sc[2][4] = {};
#pragma unroll
    for (int ni = 0; ni < 4; ++ni)
#pragma unroll
      for (int kc = 0; kc < 4; ++kc) {
        short8 bf = *(const short8*)&Kbuf[cur][((kc * 4 + quad) * 64 + ni * 16 + l15) * 8];
        sc[0][ni] = __builtin_amdgcn_mfma_f32_16x16x32_bf16(qfrag[0][kc], bf, sc[0][ni], 0, 0, 0);
        sc[1][ni] = __builtin_amdgcn_mfma_f32_16x16x32_bf16(qfrag[1][kc], bf, sc[1][ni], 0, 0, 0);
      }

    short8 pa[2][2];
#pragma unroll
    for (int rs = 0; rs < 2; ++rs) {
      const int qt64 = 2 * qt + rs;
      if (kt >= qt64) {   // diagonal or beyond: causal mask (all-masked => p=0)
        const int qrow = qt * 128 + rs * 64 + wave * 16 + quad * 4;
#pragma unroll
        for (int ni = 0; ni < 4; ++ni) {
          int kvcol = kt * 64 + ni * 16 + l15;
#pragma unroll
          for (int r = 0; r < 4; ++r)
            if (kvcol > qrow + r) sc[rs][ni][r] = -1e30f;
        }
      }

      // online softmax (raw-unit max; scale folded into exp2 args via CP)
      float alpha[4];
#pragma unroll
      for (int r = 0; r < 4; ++r) {
        float v = fmaxf(fmaxf(sc[rs][0][r], sc[rs][1][r]),
                        fmaxf(sc[rs][2][r], sc[rs][3][r]));
        v = rowmax16(v);
        float mnew = fmaxf(m_r[rs][r], v);
        alpha[r] = exp2f((m_r[rs][r] - mnew) * CP);
        m_r[rs][r] = mnew;
        float mc = mnew * CP;
#pragma unroll
        for (int ni = 0; ni < 4; ++ni) {
          float p = exp2f(sc[rs][ni][r] * CP - mc);
          pw[(quad * 4 + r) * 72 + ni * 16 + l15] = __float2bfloat16(p);
        }
      }

      // read this rowset's P fragments back, then region is reusable (same-wave
      // DS ordering guarantees the rs=1 writes land after these reads)
#pragma unroll
      for (int kk2 = 0; kk2 < 2; ++kk2)
        pa[rs][kk2] = *(const short8*)&pw[l15 * 72 + kk2 * 32 + quad * 8];

#pragma unroll
      for (int nc = 0; nc < 8; ++nc)
#pragma unroll
        for (int r = 0; r < 4; ++r) o[rs][nc][r] *= alpha[r];
#pragma unroll
      for (int r = 0; r < 4; ++r) o_l[rs][r] *= alpha[r];
    }

    // fused PV: each V fragment loaded once, used by both rowsets
#pragma unroll
    for (int kk2 = 0; kk2 < 2; ++kk2) {
#pragma unroll
      for (int nc = 0; nc < 8; ++nc) {
        int d = nc * 16 + l15;
        int swcol = (kk2 * 32 + quad * 8) ^ ((d & 7) << 3);
        short8 vv = *(const short8*)&Vbuf[cur][d * 64 + swcol];
        o[0][nc] = __builtin_amdgcn_mfma_f32_16x16x32_bf16(pa[0][kk2], vv, o[0][nc], 0, 0, 0);
        o[1][nc] = __builtin_amdgcn_mfma_f32_16x16x32_bf16(pa[1][kk2], vv, o[1][nc], 0, 0, 0);
      }
      o_l[0] = __builtin_amdgcn_mfma_f32_16x16x32_bf16(pa[0][kk2], onesb, o_l[0], 0, 0, 0);
      o_l[1] = __builtin_amdgcn_mfma_f32_16x16x32_bf16(pa[1][kk2], onesb, o_l[1], 0, 0, 0);
    }
  }

#pragma unroll
  for (int rs = 0; rs < 2; ++rs) {
    float inv[4];
#pragma unroll
    for (int r = 0; r < 4; ++r) inv[r] = 1.0f / o_l[rs][r];
    const size_t orow0 = (size_t)(b * S_LEN + qt * 128 + rs * 64 + wave * 16 + quad * 4);
#pragma unroll
    for (int nc = 0; nc < 8; ++nc)
#pragma unroll
      for (int r = 0; r < 4; ++r)
        aout[(orow0 + r) * 2048 + h * 128 + nc * 16 + l15] =
            __float2bfloat16(o[rs][nc][r] * inv[r]);
  }
}

// -------------------------------------------------------------------- launch
extern "C" void kernel_launch(void* const* d_in, const int* in_sizes, int n_in,
                              void* d_out, int out_size, void* d_ws, size_t ws_size,
                              hipStream_t stream) {
  const float* x    = (const float*)d_in[0];
  const float* cosb = (const float*)d_in[1];
  const float* sinb = (const float*)d_in[2];
  // d_in[3] = mask (causal, analytic)
  const float* Wq = (const float*)d_in[4];
  const float* Wk = (const float*)d_in[5];
  const float* Wv = (const float*)d_in[6];
  const float* Wo = (const float*)d_in[7];
  float* out = (float*)d_out;

  char* ws = (char*)d_ws;
  __hip_bfloat16* xb    = (__hip_bfloat16*)(ws);                 // 16 MB
  __hip_bfloat16* wqkvt = (__hip_bfloat16*)(ws + (16u << 20));   // 12 MB [3072][2048]
  __hip_bfloat16* wot   = (__hip_bfloat16*)(ws + (28u << 20));   // 8 MB  [2048][2048]
  __hip_bfloat16* qbuf  = (__hip_bfloat16*)(ws + (36u << 20));   // 16 MB [4096][2048]
  __hip_bfloat16* kbuf  = (__hip_bfloat16*)(ws + (52u << 20));   // 4 MB  tiles
  __hip_bfloat16* vbuf  = (__hip_bfloat16*)(ws + (56u << 20));   // 4 MB  tiles
  __hip_bfloat16* aout  = (__hip_bfloat16*)(ws + (60u << 20));   // 16 MB [4096][2048]

  prep_kernel<<<18432, 256, 0, stream>>>(x, Wq, Wk, Wv, Wo, xb, wqkvt, wot);
  qkv_gemm_kernel<<<dim3(24, 64), 256, 0, stream>>>(xb, wqkvt, qbuf, kbuf, vbuf);
  rope_kernel<<<2560, 256, 0, stream>>>(qbuf, kbuf, cosb, sinb);
  attn_kernel<<<dim3(16, 32), 256, 0, stream>>>(qbuf, kbuf, vbuf, aout);
  gemm_bt_f32_kernel<<<dim3(16, 64), 256, 0, stream>>>(aout, wot, out, 2048, 2048);
}

// Round 6
// 412.953 us; speedup vs baseline: 1.1846x; 1.1846x over previous
//
#include <hip/hip_runtime.h>
#include <hip/hip_bf16.h>
#include <cstdint>
#include <type_traits>

typedef __attribute__((ext_vector_type(8))) short short8;
typedef __attribute__((ext_vector_type(4))) float floatx4;

constexpr int S_LEN = 2048;
constexpr float ATTN_SCALE = 0.08838834764831845f;  // 128^-0.5
constexpr float LOG2E = 1.4426950408889634f;
constexpr float CP = ATTN_SCALE * LOG2E;            // fold scale into exp2 arg

// ---------------------------------------------------------------- async G->LDS
__device__ __forceinline__ void gl_lds16(const void* gp, void* lp) {
  __builtin_amdgcn_global_load_lds(
      (__attribute__((address_space(1))) void*)(uintptr_t)gp,
      (__attribute__((address_space(3))) void*)lp,
      16, 0, 0);
}

// ------------------------------------------------ 16-lane max via DPP row_ror
__device__ __forceinline__ float rowmax16(float x) {
  union { float f; int i; } a, b;
  a.f = x;
  b.i = __builtin_amdgcn_update_dpp(0, a.i, 0x121, 0xF, 0xF, true);  // ror:1
  x = fmaxf(x, b.f); a.f = x;
  b.i = __builtin_amdgcn_update_dpp(0, a.i, 0x122, 0xF, 0xF, true);  // ror:2
  x = fmaxf(x, b.f); a.f = x;
  b.i = __builtin_amdgcn_update_dpp(0, a.i, 0x124, 0xF, 0xF, true);  // ror:4
  x = fmaxf(x, b.f); a.f = x;
  b.i = __builtin_amdgcn_update_dpp(0, a.i, 0x128, 0xF, 0xF, true);  // ror:8
  return fmaxf(x, b.f);
}

// --------------------------------------------------------------------- RoPE
// out[d] = x[d]*cos[d>>1] - x[d+64]*sin[d>>1]
// out[d+64] = x[d+64]*cos[32+(d>>1)] + x[d]*sin[32+(d>>1)]
__device__ __forceinline__ void rope8(short8 x0, short8 x1, const float* ca,
                                      const float* sa, const float* cb,
                                      const float* sb, short8& y0, short8& y1) {
#pragma unroll
  for (int e = 0; e < 8; ++e) {
    union { short s; __hip_bfloat16 h; } u0, u1, w0, w1;
    u0.s = x0[e]; u1.s = x1[e];
    float f0 = __bfloat162float(u0.h), f1 = __bfloat162float(u1.h);
    int j = e >> 1;
    w0.h = __float2bfloat16(f0 * ca[j] - f1 * sa[j]);
    w1.h = __float2bfloat16(f1 * cb[j] + f0 * sb[j]);
    y0[e] = w0.s; y1[e] = w1.s;
  }
}

// ------------------------------------------------------------- fused prologue
// blocks [0,8192): x fp32 -> bf16; [8192,12288): Wq^T; [12288,13312): Wk^T;
// [13312,14336): Wv^T; [14336,18432): Wo^T
__device__ __forceinline__ void tr32(const float* __restrict__ src,
                                     __hip_bfloat16* __restrict__ dst,
                                     int blk, int nblk_x, int N, int tid,
                                     float (*tile)[33]) {
  int n0 = (blk % nblk_x) * 32, k0 = (blk / nblk_x) * 32;
  int tx = tid & 31, ty = tid >> 5;   // (32, 8)
#pragma unroll
  for (int i = ty; i < 32; i += 8)
    tile[i][tx] = src[(size_t)(k0 + i) * N + n0 + tx];
  __syncthreads();
#pragma unroll
  for (int i = ty; i < 32; i += 8)
    dst[(size_t)(n0 + i) * 2048 + k0 + tx] = __float2bfloat16(tile[tx][i]);
}

__global__ void prep_kernel(const float* __restrict__ x,
                            const float* __restrict__ Wq,
                            const float* __restrict__ Wk,
                            const float* __restrict__ Wv,
                            const float* __restrict__ Wo,
                            __hip_bfloat16* __restrict__ xb,
                            __hip_bfloat16* __restrict__ wqkvt,
                            __hip_bfloat16* __restrict__ wot) {
  __shared__ float tile[32][33];
  int bx = blockIdx.x, tid = threadIdx.x;
  if (bx < 8192) {
    int i = bx * 256 + tid;           // 2097152 float4s exactly
    float4 f = reinterpret_cast<const float4*>(x)[i];
    union { unsigned long long u64; __hip_bfloat16 h[4]; } u;
    u.h[0] = __float2bfloat16(f.x);
    u.h[1] = __float2bfloat16(f.y);
    u.h[2] = __float2bfloat16(f.z);
    u.h[3] = __float2bfloat16(f.w);
    reinterpret_cast<unsigned long long*>(xb)[i] = u.u64;
  } else if (bx < 12288) {
    tr32(Wq, wqkvt, bx - 8192, 64, 2048, tid, tile);
  } else if (bx < 13312) {
    tr32(Wk, wqkvt + 2048 * 2048, bx - 12288, 16, 512, tid, tile);
  } else if (bx < 14336) {
    tr32(Wv, wqkvt + 2560 * 2048, bx - 13312, 16, 512, tid, tile);
  } else {
    tr32(Wo, wot, bx - 14336, 64, 2048, tid, tile);
  }
}

// ------------------------------------------------------------ QKV GEMM (fused)
// C = xb[4096][2048] @ wqkvt[3072][2048]^T. 128x128 tile, 4 waves (2x2), BK=64,
// global_load_lds chunk-transposed staging (round-4 structure, proven).
// Epilogue: C-tile round-trips through the 32 KB staging LDS; RoPE applied
// in-register for Q/K regions; all regions written with vectorized short8:
//   cols 0..2047    -> qbuf[row][col] (roped)
//   cols 2048..2559 -> kbuf chunk-transposed tiles (roped):
//                      (kv,d) at tile*8192 + (d>>3)*512 + kv*8 + (d&7)
//   cols 2560..3071 -> vbuf V^T XOR-swizzled tiles:
//                      (kv,d) at tile*8192 + d*64 + (kv ^ ((d&7)<<3))
__global__ __launch_bounds__(256, 2) void qkv_gemm_kernel(
    const __hip_bfloat16* __restrict__ A,
    const __hip_bfloat16* __restrict__ Bt,
    __hip_bfloat16* __restrict__ qbuf,
    __hip_bfloat16* __restrict__ kbuf,
    __hip_bfloat16* __restrict__ vbuf,
    const float* __restrict__ cosb,
    const float* __restrict__ sinb) {
  constexpr int K = 2048;
  __shared__ __align__(16) __hip_bfloat16 lds[2 * 128 * 64];  // 32 KB
  const int tid = threadIdx.x;
  const int wave = tid >> 6, lane = tid & 63;
  const int quad = lane >> 4, l15 = lane & 15;
  const int wm = wave >> 1, wn = wave & 1;
  const int m0 = blockIdx.y * 128, n0 = blockIdx.x * 128;

  floatx4 acc[4][4] = {};
  const __hip_bfloat16* Ab = A + (size_t)m0 * K;
  const __hip_bfloat16* Bb = Bt + (size_t)n0 * K;
  const int i0 = wave * 4;

  for (int k0 = 0; k0 < K; k0 += 64) {
#pragma unroll
    for (int j = 0; j < 4; ++j) {
      const int i = i0 + j;
      const int kchunk = i >> 1;
      const int row = ((i & 1) << 6) | lane;
      gl_lds16(Ab + (size_t)row * K + (k0 + kchunk * 8), &lds[i * 512]);
      gl_lds16(Bb + (size_t)row * K + (k0 + kchunk * 8), &lds[8192 + i * 512]);
    }
    __syncthreads();
#pragma unroll
    for (int kk = 0; kk < 2; ++kk) {
      short8 a[4], b[4];
#pragma unroll
      for (int mi = 0; mi < 4; ++mi)
        a[mi] = *(const short8*)&lds[((((kk << 2) | quad) * 128) + wm * 64 + mi * 16 + l15) * 8];
#pragma unroll
      for (int ni = 0; ni < 4; ++ni)
        b[ni] = *(const short8*)&lds[8192 + ((((kk << 2) | quad) * 128) + wn * 64 + ni * 16 + l15) * 8];
#pragma unroll
      for (int mi = 0; mi < 4; ++mi)
#pragma unroll
        for (int ni = 0; ni < 4; ++ni)
          acc[mi][ni] = __builtin_amdgcn_mfma_f32_16x16x32_bf16(a[mi], b[ni], acc[mi][ni], 0, 0, 0);
    }
    __syncthreads();
  }

  // ---- epilogue: C-tile -> LDS (bf16), then region-specific vector writes
  const bool isv = (n0 >= 2560);
  short* lds2 = (short*)lds;                       // [128][128] bf16 = 32 KB
#pragma unroll
  for (int mi = 0; mi < 4; ++mi)
#pragma unroll
    for (int ni = 0; ni < 4; ++ni)
#pragma unroll
      for (int r = 0; r < 4; ++r) {
        int row = wm * 64 + mi * 16 + quad * 4 + r;  // C/D: row = quad*4+reg
        int col = wn * 64 + ni * 16 + l15;           //      col = lane&15
        union { short s; __hip_bfloat16 h; } u;
        u.h = __float2bfloat16(acc[mi][ni][r]);
        if (isv) lds2[col * 128 + row] = u.s;        // V stored transposed
        else     lds2[row * 128 + col] = u.s;
      }
  __syncthreads();

  const int c8 = tid & 7, d0 = c8 * 8;
  if (n0 < 2048) {
    // ---- Q: rope + row-major coalesced write
#pragma unroll
    for (int j = 0; j < 4; ++j) {
      int rr = (tid >> 3) + 32 * j;
      int rowg = m0 + rr;
      int s = rowg & (S_LEN - 1);
      float ca[4], sa[4], cb[4], sb[4];
      *(float4*)ca = *(const float4*)&cosb[s * 64 + c8 * 4];
      *(float4*)sa = *(const float4*)&sinb[s * 64 + c8 * 4];
      *(float4*)cb = *(const float4*)&cosb[s * 64 + 32 + c8 * 4];
      *(float4*)sb = *(const float4*)&sinb[s * 64 + 32 + c8 * 4];
      short8 x0 = *(const short8*)&lds2[rr * 128 + d0];
      short8 x1 = *(const short8*)&lds2[rr * 128 + 64 + d0];
      short8 y0, y1;
      rope8(x0, x1, ca, sa, cb, sb, y0, y1);
      *(short8*)(qbuf + (size_t)rowg * 2048 + n0 + d0) = y0;
      *(short8*)(qbuf + (size_t)rowg * 2048 + n0 + 64 + d0) = y1;
    }
  } else if (!isv) {
    // ---- K: rope + chunk-transposed tile write (contiguous short8 runs)
    const int kvh = (n0 - 2048) >> 7;
#pragma unroll
    for (int j = 0; j < 4; ++j) {
      int rr = (tid >> 3) + 32 * j;
      int rowg = m0 + rr;
      int s = rowg & (S_LEN - 1), bb = rowg >> 11;
      int kv = s & 63;
      size_t tb = ((size_t)(bb * 4 + kvh) * 32 + (s >> 6)) * 8192;
      float ca[4], sa[4], cb[4], sb[4];
      *(float4*)ca = *(const float4*)&cosb[s * 64 + c8 * 4];
      *(float4*)sa = *(const float4*)&sinb[s * 64 + c8 * 4];
      *(float4*)cb = *(const float4*)&cosb[s * 64 + 32 + c8 * 4];
      *(float4*)sb = *(const float4*)&sinb[s * 64 + 32 + c8 * 4];
      short8 x0 = *(const short8*)&lds2[rr * 128 + d0];
      short8 x1 = *(const short8*)&lds2[rr * 128 + 64 + d0];
      short8 y0, y1;
      rope8(x0, x1, ca, sa, cb, sb, y0, y1);
      *(short8*)(kbuf + tb + (size_t)c8 * 512 + kv * 8) = y0;
      *(short8*)(kbuf + tb + (size_t)(8 + c8) * 512 + kv * 8) = y1;
    }
  } else {
    // ---- V: transposed XOR-swizzled tile write (contiguous short8 runs)
    const int kvh = (n0 - 2560) >> 7;
    const int bb = m0 >> 11;
    const int kt0 = (m0 & (S_LEN - 1)) >> 6;
    const int kv0 = c8 * 8;
#pragma unroll
    for (int j = 0; j < 4; ++j) {
      int d = (tid >> 3) + 32 * j;
      int cxor = (d & 7) << 3;
#pragma unroll
      for (int half = 0; half < 2; ++half) {
        short8 vv = *(const short8*)&lds2[d * 128 + half * 64 + kv0];
        size_t tb = ((size_t)(bb * 4 + kvh) * 32 + kt0 + half) * 8192;
        *(short8*)(vbuf + tb + d * 64 + (kv0 ^ cxor)) = vv;
      }
    }
  }
}

// --------------------------------------------------------------- AO GEMM
__global__ __launch_bounds__(256, 2) void gemm_bt_f32_kernel(
    const __hip_bfloat16* __restrict__ A,
    const __hip_bfloat16* __restrict__ Bt,
    float* __restrict__ C, int N, int K) {
  __shared__ __align__(16) __hip_bfloat16 lds[2 * 128 * 64];
  const int tid = threadIdx.x;
  const int wave = tid >> 6, lane = tid & 63;
  const int quad = lane >> 4, l15 = lane & 15;
  const int wm = wave >> 1, wn = wave & 1;
  const int m0 = blockIdx.y * 128, n0 = blockIdx.x * 128;

  floatx4 acc[4][4] = {};
  const __hip_bfloat16* Ab = A + (size_t)m0 * K;
  const __hip_bfloat16* Bb = Bt + (size_t)n0 * K;
  const int i0 = wave * 4;

  for (int k0 = 0; k0 < K; k0 += 64) {
#pragma unroll
    for (int j = 0; j < 4; ++j) {
      const int i = i0 + j;
      const int kchunk = i >> 1;
      const int row = ((i & 1) << 6) | lane;
      gl_lds16(Ab + (size_t)row * K + (k0 + kchunk * 8), &lds[i * 512]);
      gl_lds16(Bb + (size_t)row * K + (k0 + kchunk * 8), &lds[8192 + i * 512]);
    }
    __syncthreads();
#pragma unroll
    for (int kk = 0; kk < 2; ++kk) {
      short8 a[4], b[4];
#pragma unroll
      for (int mi = 0; mi < 4; ++mi)
        a[mi] = *(const short8*)&lds[((((kk << 2) | quad) * 128) + wm * 64 + mi * 16 + l15) * 8];
#pragma unroll
      for (int ni = 0; ni < 4; ++ni)
        b[ni] = *(const short8*)&lds[8192 + ((((kk << 2) | quad) * 128) + wn * 64 + ni * 16 + l15) * 8];
#pragma unroll
      for (int mi = 0; mi < 4; ++mi)
#pragma unroll
        for (int ni = 0; ni < 4; ++ni)
          acc[mi][ni] = __builtin_amdgcn_mfma_f32_16x16x32_bf16(a[mi], b[ni], acc[mi][ni], 0, 0, 0);
    }
    __syncthreads();
  }

#pragma unroll
  for (int mi = 0; mi < 4; ++mi)
#pragma unroll
    for (int ni = 0; ni < 4; ++ni)
#pragma unroll
      for (int r = 0; r < 4; ++r) {
        int row = m0 + wm * 64 + mi * 16 + quad * 4 + r;
        int col = n0 + wn * 64 + ni * 16 + l15;
        C[(size_t)row * N + col] = acc[mi][ni][r];
      }
}

// ---------------------------------------------------------------- attention
// grid (16, 32), 256 thr. Block = 128 q-rows (2 rowsets of 64) x one head.
// K,V: double-buffered coalesced global_load_lds DMA (K chunk-transposed,
// V transposed+XOR-swizzled). One barrier per KV tile. Fused PV pass shares
// each V fragment across both rowsets.
__global__ __launch_bounds__(256, 2) void attn_kernel(
    const __hip_bfloat16* __restrict__ qbuf,   // [4096][2048]
    const __hip_bfloat16* __restrict__ kbuf,   // tiles
    const __hip_bfloat16* __restrict__ vbuf,   // tiles
    __hip_bfloat16* __restrict__ aout) {       // [4096][2048]
  const int qt = (blockIdx.y & 16) ? blockIdx.x : (15 - blockIdx.x);
  const int bh = blockIdx.y;
  const int b = bh >> 4, h = bh & 15;
  const int kvh = h >> 2;

  __shared__ __align__(16) __hip_bfloat16 Kbuf[2][8192];      // 2 x 16 KB
  __shared__ __align__(16) __hip_bfloat16 Vbuf[2][8192];      // 2 x 16 KB
  __shared__ __align__(16) __hip_bfloat16 Plds[4 * 16 * 72];  // 9 KB

  const int tid = threadIdx.x;
  const int wave = tid >> 6, lane = tid & 63;
  const int quad = lane >> 4, l15 = lane & 15;

  short8 qfrag[2][4];
#pragma unroll
  for (int rs = 0; rs < 2; ++rs)
#pragma unroll
    for (int kc = 0; kc < 4; ++kc)
      qfrag[rs][kc] = *(const short8*)(qbuf +
          (size_t)(b * S_LEN + qt * 128 + rs * 64 + wave * 16 + l15) * 2048 +
          h * 128 + kc * 32 + quad * 8);

  const __hip_bfloat16* ktiles = kbuf + (size_t)(b * 4 + kvh) * 32 * 8192;
  const __hip_bfloat16* vtiles = vbuf + (size_t)(b * 4 + kvh) * 32 * 8192;
  const int nt = 2 * qt + 2;

#pragma unroll
  for (int j = 0; j < 4; ++j) {
    int c = tid + 256 * j;
    gl_lds16(ktiles + c * 8, &Kbuf[0][c * 8]);
    gl_lds16(vtiles + c * 8, &Vbuf[0][c * 8]);
  }

  float m_r[2][4];
  floatx4 o[2][8] = {};
  floatx4 o_l[2] = {};
#pragma unroll
  for (int rs = 0; rs < 2; ++rs)
#pragma unroll
    for (int r = 0; r < 4; ++r) m_r[rs][r] = -1e30f;

  short8 onesb;
#pragma unroll
  for (int e = 0; e < 8; ++e) onesb[e] = (short)0x3F80;  // bf16 1.0

  __hip_bfloat16* pw = &Plds[wave * 16 * 72];

  for (int kt = 0; kt < nt; ++kt) {
    const int cur = kt & 1;
    __syncthreads();   // K(kt)/V(kt) DMA drained & visible

    if (kt + 1 < nt) {
      const __hip_bfloat16* kb = ktiles + (size_t)(kt + 1) * 8192;
      const __hip_bfloat16* vb = vtiles + (size_t)(kt + 1) * 8192;
#pragma unroll
      for (int j = 0; j < 4; ++j) {
        int c = tid + 256 * j;
        gl_lds16(kb + c * 8, &Kbuf[1 - cur][c * 8]);
        gl_lds16(vb + c * 8, &Vbuf[1 - cur][c * 8]);
      }
    }

    // S = Q K^T for both rowsets (K frags loaded once, used twice)
    floatx4 sc[2][4] = {};
#pragma unroll
    for (int ni = 0; ni < 4; ++ni)
#pragma unroll
      for (int kc = 0; kc < 4; ++kc) {
        short8 bf = *(const short8*)&Kbuf[cur][((kc * 4 + quad) * 64 + ni * 16 + l15) * 8];
        sc[0][ni] = __builtin_amdgcn_mfma_f32_16x16x32_bf16(qfrag[0][kc], bf, sc[0][ni], 0, 0, 0);
        sc[1][ni] = __builtin_amdgcn_mfma_f32_16x16x32_bf16(qfrag[1][kc], bf, sc[1][ni], 0, 0, 0);
      }

    short8 pa[2][2];
#pragma unroll
    for (int rs = 0; rs < 2; ++rs) {
      const int qt64 = 2 * qt + rs;
      if (kt >= qt64) {   // diagonal or beyond: causal mask (all-masked => p=0)
        const int qrow = qt * 128 + rs * 64 + wave * 16 + quad * 4;
#pragma unroll
        for (int ni = 0; ni < 4; ++ni) {
          int kvcol = kt * 64 + ni * 16 + l15;
#pragma unroll
          for (int r = 0; r < 4; ++r)
            if (kvcol > qrow + r) sc[rs][ni][r] = -1e30f;
        }
      }

      // online softmax (raw-unit max; scale folded into exp2 args via CP)
      float alpha[4];
#pragma unroll
      for (int r = 0; r < 4; ++r) {
        float v = fmaxf(fmaxf(sc[rs][0][r], sc[rs][1][r]),
                        fmaxf(sc[rs][2][r], sc[rs][3][r]));
        v = rowmax16(v);
        float mnew = fmaxf(m_r[rs][r], v);
        alpha[r] = exp2f((m_r[rs][r] - mnew) * CP);
        m_r[rs][r] = mnew;
        float mc = mnew * CP;
#pragma unroll
        for (int ni = 0; ni < 4; ++ni) {
          float p = exp2f(sc[rs][ni][r] * CP - mc);
          pw[(quad * 4 + r) * 72 + ni * 16 + l15] = __float2bfloat16(p);
        }
      }

      // read this rowset's P frags back, then region is reusable (same-wave
      // DS ordering guarantees rs=1 writes land after these reads)
#pragma unroll
      for (int kk2 = 0; kk2 < 2; ++kk2)
        pa[rs][kk2] = *(const short8*)&pw[l15 * 72 + kk2 * 32 + quad * 8];

#pragma unroll
      for (int nc = 0; nc < 8; ++nc)
#pragma unroll
        for (int r = 0; r < 4; ++r) o[rs][nc][r] *= alpha[r];
#pragma unroll
      for (int r = 0; r < 4; ++r) o_l[rs][r] *= alpha[r];
    }

    // fused PV: each V fragment loaded once, used by both rowsets
#pragma unroll
    for (int kk2 = 0; kk2 < 2; ++kk2) {
#pragma unroll
      for (int nc = 0; nc < 8; ++nc) {
        int d = nc * 16 + l15;
        int swcol = (kk2 * 32 + quad * 8) ^ ((d & 7) << 3);
        short8 vv = *(const short8*)&Vbuf[cur][d * 64 + swcol];
        o[0][nc] = __builtin_amdgcn_mfma_f32_16x16x32_bf16(pa[0][kk2], vv, o[0][nc], 0, 0, 0);
        o[1][nc] = __builtin_amdgcn_mfma_f32_16x16x32_bf16(pa[1][kk2], vv, o[1][nc], 0, 0, 0);
      }
      o_l[0] = __builtin_amdgcn_mfma_f32_16x16x32_bf16(pa[0][kk2], onesb, o_l[0], 0, 0, 0);
      o_l[1] = __builtin_amdgcn_mfma_f32_16x16x32_bf16(pa[1][kk2], onesb, o_l[1], 0, 0, 0);
    }
  }

#pragma unroll
  for (int rs = 0; rs < 2; ++rs) {
    float inv[4];
#pragma unroll
    for (int r = 0; r < 4; ++r) inv[r] = 1.0f / o_l[rs][r];
    const size_t orow0 = (size_t)(b * S_LEN + qt * 128 + rs * 64 + wave * 16 + quad * 4);
#pragma unroll
    for (int nc = 0; nc < 8; ++nc)
#pragma unroll
      for (int r = 0; r < 4; ++r)
        aout[(orow0 + r) * 2048 + h * 128 + nc * 16 + l15] =
            __float2bfloat16(o[rs][nc][r] * inv[r]);
  }
}

// -------------------------------------------------------------------- launch
extern "C" void kernel_launch(void* const* d_in, const int* in_sizes, int n_in,
                              void* d_out, int out_size, void* d_ws, size_t ws_size,
                              hipStream_t stream) {
  const float* x    = (const float*)d_in[0];
  const float* cosb = (const float*)d_in[1];
  const float* sinb = (const float*)d_in[2];
  // d_in[3] = mask (causal, analytic)
  const float* Wq = (const float*)d_in[4];
  const float* Wk = (const float*)d_in[5];
  const float* Wv = (const float*)d_in[6];
  const float* Wo = (const float*)d_in[7];
  float* out = (float*)d_out;

  char* ws = (char*)d_ws;
  __hip_bfloat16* xb    = (__hip_bfloat16*)(ws);                 // 16 MB
  __hip_bfloat16* wqkvt = (__hip_bfloat16*)(ws + (16u << 20));   // 12 MB [3072][2048]
  __hip_bfloat16* wot   = (__hip_bfloat16*)(ws + (28u << 20));   // 8 MB  [2048][2048]
  __hip_bfloat16* qbuf  = (__hip_bfloat16*)(ws + (36u << 20));   // 16 MB [4096][2048]
  __hip_bfloat16* kbuf  = (__hip_bfloat16*)(ws + (52u << 20));   // 4 MB  tiles
  __hip_bfloat16* vbuf  = (__hip_bfloat16*)(ws + (56u << 20));   // 4 MB  tiles
  __hip_bfloat16* aout  = (__hip_bfloat16*)(ws + (60u << 20));   // 16 MB [4096][2048]

  prep_kernel<<<18432, 256, 0, stream>>>(x, Wq, Wk, Wv, Wo, xb, wqkvt, wot);
  qkv_gemm_kernel<<<dim3(24, 32), 256, 0, stream>>>(xb, wqkvt, qbuf, kbuf, vbuf, cosb, sinb);
  attn_kernel<<<dim3(16, 32), 256, 0, stream>>>(qbuf, kbuf, vbuf, aout);
  gemm_bt_f32_kernel<<<dim3(16, 32), 256, 0, stream>>>(aout, wot, out, 2048, 2048);
}